// Round 2
// baseline (142.979 us; speedup 1.0000x reference)
//
#include <hip/hip_runtime.h>

#define B_SZ 256
#define D_SZ 256
#define M_SZ 65536
#define C_SZ 1000
#define TEMP 0.05f
#define EPSF 1e-6f

// ---- ws layout (bytes) ----
#define OFF_FCT     0          // float[D_SZ*C_SZ] = 1,024,000 B (transposed, pre-scaled)
#define OFF_NUMS    1024000    // int[C_SZ]
#define OFF_OFFS    1028096    // int[C_SZ]
#define OFF_MEMB    1032192    // int[M_SZ] = 262,144 B
#define OFF_ACC     1294336    // float[2]
#define OFF_CNT     1294344    // int[1]

// Single-block counting sort: histogram (LDS atomics) -> scan -> scatter.
// Also zero-initializes acc/cnt so no hipMemsetAsync dispatches are needed.
__launch_bounds__(1024)
__global__ void k_sort(const int* __restrict__ labels, int* __restrict__ nums,
                       int* __restrict__ offs, int* __restrict__ members,
                       float* __restrict__ acc, int* __restrict__ cnt) {
    __shared__ int h[C_SZ];
    __shared__ int sc[1024];
    int t = threadIdx.x;
    if (t < C_SZ) h[t] = 0;
    if (t == 0) { acc[0] = 0.f; acc[1] = 0.f; cnt[0] = 0; }
    __syncthreads();
    for (int m = t; m < M_SZ; m += 1024) atomicAdd(&h[labels[m]], 1);
    __syncthreads();
    int own = (t < C_SZ) ? h[t] : 0;
    sc[t] = own;
    __syncthreads();
    // Hillis-Steele inclusive scan over 1024
    for (int d = 1; d < 1024; d <<= 1) {
        int v = (t >= d) ? sc[t - d] : 0;
        __syncthreads();
        sc[t] += v;
        __syncthreads();
    }
    int excl = sc[t] - own;
    if (t < C_SZ) { nums[t] = own; offs[t] = excl; }
    __syncthreads();
    if (t < C_SZ) h[t] = excl;  // reuse as running scatter cursor
    __syncthreads();
    for (int m = t; m < M_SZ; m += 1024) {
        int c = labels[m];
        int pos = atomicAdd(&h[c], 1);
        members[pos] = m;
    }
}

// One block per class: sum member rows, unrolled x8 so 8 independent row
// loads are in flight (kills the serial latency chain). Writes transposed +
// pre-scaled: fct[d*C + c] = sum / (TEMP * max(n,1)).
__launch_bounds__(256)
__global__ void k_classsum(const float* __restrict__ features,
                           const int* __restrict__ members,
                           const int* __restrict__ offs,
                           const int* __restrict__ nums,
                           float* __restrict__ fct) {
    int c = blockIdx.x;
    int t = threadIdx.x;
    int beg = offs[c], n = nums[c];
    float a0 = 0.f, a1 = 0.f, a2 = 0.f, a3 = 0.f;
    float a4 = 0.f, a5 = 0.f, a6 = 0.f, a7 = 0.f;
    int i = 0;
    for (; i + 8 <= n; i += 8) {
        int r0 = members[beg + i + 0];
        int r1 = members[beg + i + 1];
        int r2 = members[beg + i + 2];
        int r3 = members[beg + i + 3];
        int r4 = members[beg + i + 4];
        int r5 = members[beg + i + 5];
        int r6 = members[beg + i + 6];
        int r7 = members[beg + i + 7];
        a0 += features[(size_t)r0 * D_SZ + t];
        a1 += features[(size_t)r1 * D_SZ + t];
        a2 += features[(size_t)r2 * D_SZ + t];
        a3 += features[(size_t)r3 * D_SZ + t];
        a4 += features[(size_t)r4 * D_SZ + t];
        a5 += features[(size_t)r5 * D_SZ + t];
        a6 += features[(size_t)r6 * D_SZ + t];
        a7 += features[(size_t)r7 * D_SZ + t];
    }
    for (; i < n; ++i) a0 += features[(size_t)members[beg + i] * D_SZ + t];
    float s = ((a0 + a1) + (a2 + a3)) + ((a4 + a5) + (a6 + a7));
    float scale = 1.0f / (TEMP * (float)(n > 0 ? n : 1));
    fct[(size_t)t * C_SZ + c] = s * scale;
}

// Fused: normalize 4 feat rows, sim = x . Fct, masked softmax (reference
// numerics), loss partials, and final combine via atomic ticket.
__launch_bounds__(256)
__global__ void k_loss(const float* __restrict__ feat,
                       const float* __restrict__ fct,
                       const int* __restrict__ nums,
                       const float* __restrict__ soft,
                       const int* __restrict__ indexes,
                       const int* __restrict__ labels,
                       const int* __restrict__ bil,
                       const int* __restrict__ cur_epoch,
                       float* __restrict__ acc, int* __restrict__ cnt,
                       float* __restrict__ out) {
    __shared__ float xs[4][D_SZ];
    __shared__ float red[4];
    __shared__ float denom[4];
    __shared__ int tgt[4];
    __shared__ int srow[4];

    int t = threadIdx.x;
    int wid = t >> 6, lane = t & 63;
    int b0 = blockIdx.x * 4;

    // normalize 4 rows into LDS
    for (int bb = 0; bb < 4; ++bb) {
        float v = feat[(size_t)(b0 + bb) * D_SZ + t];
        float s = v * v;
        #pragma unroll
        for (int o = 32; o; o >>= 1) s += __shfl_down(s, o);
        if (lane == 0) red[wid] = s;
        __syncthreads();
        float nrm = fmaxf(sqrtf(red[0] + red[1] + red[2] + red[3]), 1e-12f);
        xs[bb][t] = v / nrm;
        __syncthreads();
    }
    if (t < 4) {
        tgt[t] = labels[indexes[b0 + t]];
        srow[t] = bil[b0 + t];
    }
    __syncthreads();

    // sim + exp for 4 class-chunks x 4 batch rows
    float er[4][4];
    float part[4] = {0.f, 0.f, 0.f, 0.f};
    #pragma unroll
    for (int k = 0; k < 4; ++k) {
        int c = t + 256 * k;
        float a0 = 0.f, a1 = 0.f, a2 = 0.f, a3 = 0.f;
        float mk = 0.f;
        if (c < C_SZ) {
            for (int i = 0; i < D_SZ; ++i) {
                float f = fct[(size_t)i * C_SZ + c];  // coalesced across lanes
                a0 = fmaf(xs[0][i], f, a0);
                a1 = fmaf(xs[1][i], f, a1);
                a2 = fmaf(xs[2][i], f, a2);
                a3 = fmaf(xs[3][i], f, a3);
            }
            mk = (nums[c] > 0) ? 1.f : 0.f;
        }
        er[k][0] = (c < C_SZ) ? __expf(a0) * mk : 0.f;
        er[k][1] = (c < C_SZ) ? __expf(a1) * mk : 0.f;
        er[k][2] = (c < C_SZ) ? __expf(a2) * mk : 0.f;
        er[k][3] = (c < C_SZ) ? __expf(a3) * mk : 0.f;
        part[0] += er[k][0]; part[1] += er[k][1];
        part[2] += er[k][2]; part[3] += er[k][3];
    }

    // per-row denominators
    #pragma unroll
    for (int bb = 0; bb < 4; ++bb) {
        float s = part[bb];
        #pragma unroll
        for (int o = 32; o; o >>= 1) s += __shfl_down(s, o);
        __syncthreads();
        if (lane == 0) red[wid] = s;
        __syncthreads();
        if (t == 0) denom[bb] = red[0] + red[1] + red[2] + red[3];
    }
    __syncthreads();

    // loss partials
    float p1 = 0.f, p2 = 0.f;
    for (int bb = 0; bb < 4; ++bb) {
        const float* sp = soft + (size_t)srow[bb] * C_SZ;
        float inv_dn = 1.0f / (denom[bb] + EPSF);
        #pragma unroll
        for (int k = 0; k < 4; ++k) {
            int c = t + 256 * k;
            if (c < C_SZ) {
                float logp = __logf(er[k][bb] * inv_dn + EPSF);
                p2 -= sp[c] * logp;
                if (c == tgt[bb]) p1 -= logp;
            }
        }
    }
    #pragma unroll
    for (int o = 32; o; o >>= 1) {
        p1 += __shfl_down(p1, o);
        p2 += __shfl_down(p2, o);
    }
    __shared__ float r1[4], r2[4];
    if (lane == 0) { r1[wid] = p1; r2[wid] = p2; }
    __syncthreads();
    if (t == 0) {
        atomicAdd(&acc[0], r1[0] + r1[1] + r1[2] + r1[3]);
        atomicAdd(&acc[1], r2[0] + r2[1] + r2[2] + r2[3]);
        __threadfence();
        int done = atomicAdd(cnt, 1);
        if (done == (int)gridDim.x - 1) {
            // all blocks' adds are visible (each did add -> fence -> inc)
            float l1 = atomicAdd(&acc[0], 0.f) / (float)B_SZ;
            float l2 = atomicAdd(&acc[1], 0.f) / (float)B_SZ;
            out[0] = (cur_epoch[0] == 0) ? l1 : 0.5f * (l1 + l2);
        }
    }
}

extern "C" void kernel_launch(void* const* d_in, const int* in_sizes, int n_in,
                              void* d_out, int out_size, void* d_ws, size_t ws_size,
                              hipStream_t stream) {
    const float* feat     = (const float*)d_in[0];
    const float* features = (const float*)d_in[1];
    const float* soft     = (const float*)d_in[2];
    const int* indexes    = (const int*)d_in[3];
    const int* labels     = (const int*)d_in[4];
    const int* bil        = (const int*)d_in[5];
    const int* cur_epoch  = (const int*)d_in[6];

    char* ws = (char*)d_ws;
    float* fct   = (float*)(ws + OFF_FCT);
    int* nums    = (int*)(ws + OFF_NUMS);
    int* offs    = (int*)(ws + OFF_OFFS);
    int* members = (int*)(ws + OFF_MEMB);
    float* acc   = (float*)(ws + OFF_ACC);
    int* cnt     = (int*)(ws + OFF_CNT);

    k_sort<<<1, 1024, 0, stream>>>(labels, nums, offs, members, acc, cnt);
    k_classsum<<<C_SZ, 256, 0, stream>>>(features, members, offs, nums, fct);
    k_loss<<<B_SZ / 4, 256, 0, stream>>>(feat, fct, nums, soft, indexes, labels,
                                         bil, cur_epoch, acc, cnt, (float*)d_out);
}

// Round 3
// 93.567 us; speedup vs baseline: 1.5281x; 1.5281x over previous
//
#include <hip/hip_runtime.h>

#define B_SZ 256
#define D_SZ 256
#define M_SZ 65536
#define C_SZ 1000
#define TEMP 0.05f
#define EPSF 1e-6f

// ---- ws layout (bytes) ----
#define OFF_FCT   0          // float[D_SZ*C_SZ] = 1,024,000 B (transposed, pre-scaled)
#define OFF_NUMS  1024000    // int[C_SZ]      (4000 B)   --+
#define OFF_ACC   1028000    // float[2]       (8 B)        | one 4012-B memset
#define OFF_CNT   1028008    // int[1]         (4 B)      --+
#define OFF_OFFS  1028096    // int[C_SZ]
#define OFF_RUN   1032192    // int[C_SZ]
#define OFF_MEMB  1036288    // int[M_SZ] = 262,144 B

// Parallel histogram: 65536 global atomics spread over 1000 addresses.
__global__ void k_hist(const int* __restrict__ labels, int* __restrict__ nums) {
    int m = blockIdx.x * blockDim.x + threadIdx.x;
    atomicAdd(&nums[labels[m]], 1);
}

// Single-block exclusive scan over class counts -> offs, run.
__launch_bounds__(1024)
__global__ void k_scan(const int* __restrict__ nums, int* __restrict__ offs,
                       int* __restrict__ run) {
    __shared__ int sc[1024];
    int t = threadIdx.x;
    int own = (t < C_SZ) ? nums[t] : 0;
    sc[t] = own;
    __syncthreads();
    for (int d = 1; d < 1024; d <<= 1) {
        int v = (t >= d) ? sc[t - d] : 0;
        __syncthreads();
        sc[t] += v;
        __syncthreads();
    }
    if (t < C_SZ) {
        int e = sc[t] - own;
        offs[t] = e;
        run[t] = e;
    }
}

// Parallel scatter (counting-sort placement).
__global__ void k_scatter(const int* __restrict__ labels, int* __restrict__ run,
                          int* __restrict__ members) {
    int m = blockIdx.x * blockDim.x + threadIdx.x;
    int c = labels[m];
    int pos = atomicAdd(&run[c], 1);
    members[pos] = m;
}

// One block per class: sum member rows, 8-way unrolled for MLP. Writes
// transposed + pre-scaled: fct[d*C + c] = sum / (TEMP * max(n,1)).
__launch_bounds__(256)
__global__ void k_classsum(const float* __restrict__ features,
                           const int* __restrict__ members,
                           const int* __restrict__ offs,
                           const int* __restrict__ nums,
                           float* __restrict__ fct) {
    int c = blockIdx.x;
    int t = threadIdx.x;
    int beg = offs[c], n = nums[c];
    float a0 = 0.f, a1 = 0.f, a2 = 0.f, a3 = 0.f;
    float a4 = 0.f, a5 = 0.f, a6 = 0.f, a7 = 0.f;
    int i = 0;
    for (; i + 8 <= n; i += 8) {
        int r0 = members[beg + i + 0];
        int r1 = members[beg + i + 1];
        int r2 = members[beg + i + 2];
        int r3 = members[beg + i + 3];
        int r4 = members[beg + i + 4];
        int r5 = members[beg + i + 5];
        int r6 = members[beg + i + 6];
        int r7 = members[beg + i + 7];
        a0 += features[(size_t)r0 * D_SZ + t];
        a1 += features[(size_t)r1 * D_SZ + t];
        a2 += features[(size_t)r2 * D_SZ + t];
        a3 += features[(size_t)r3 * D_SZ + t];
        a4 += features[(size_t)r4 * D_SZ + t];
        a5 += features[(size_t)r5 * D_SZ + t];
        a6 += features[(size_t)r6 * D_SZ + t];
        a7 += features[(size_t)r7 * D_SZ + t];
    }
    for (; i < n; ++i) a0 += features[(size_t)members[beg + i] * D_SZ + t];
    float s = ((a0 + a1) + (a2 + a3)) + ((a4 + a5) + (a6 + a7));
    float scale = 1.0f / (TEMP * (float)(n > 0 ? n : 1));
    fct[(size_t)t * C_SZ + c] = s * scale;
}

// One block (1024 thr, 16 waves) per batch row; thread t = class t.
// Normalize row, sim = x.Fct (coalesced), masked softmax (reference
// numerics), loss partials, ticket-fused finalize.
__launch_bounds__(1024)
__global__ void k_loss(const float* __restrict__ feat,
                       const float* __restrict__ fct,
                       const int* __restrict__ nums,
                       const float* __restrict__ soft,
                       const int* __restrict__ indexes,
                       const int* __restrict__ labels,
                       const int* __restrict__ bil,
                       const int* __restrict__ cur_epoch,
                       float* __restrict__ acc, int* __restrict__ cnt,
                       float* __restrict__ out) {
    __shared__ float xs[D_SZ];
    __shared__ float wred[16];
    __shared__ float wred2[16];
    __shared__ float bcast;
    __shared__ int tgt_s, srow_s;

    int t = threadIdx.x;
    int r = blockIdx.x;
    int lane = t & 63, wid = t >> 6;

    if (t == 0) {
        tgt_s = labels[indexes[r]];
        srow_s = bil[r];
    }

    // ---- normalize row r into xs ----
    float v = (t < D_SZ) ? feat[(size_t)r * D_SZ + t] : 0.f;
    float s = v * v;
    #pragma unroll
    for (int o = 32; o; o >>= 1) s += __shfl_down(s, o);
    if (lane == 0) wred[wid] = s;
    __syncthreads();
    if (t == 0) {
        float z = 0.f;
        #pragma unroll
        for (int i = 0; i < 16; ++i) z += wred[i];
        bcast = fmaxf(sqrtf(z), 1e-12f);
    }
    __syncthreads();
    if (t < D_SZ) xs[t] = v / bcast;
    __syncthreads();

    // ---- sim + exp for class t ----
    float a = 0.f;
    if (t < C_SZ) {
        #pragma unroll 4
        for (int i = 0; i < D_SZ; ++i)
            a = fmaf(xs[i], fct[(size_t)i * C_SZ + t], a);
    }
    float e = 0.f;
    if (t < C_SZ && nums[t] > 0) e = __expf(a);

    // ---- denominator over classes ----
    s = e;
    #pragma unroll
    for (int o = 32; o; o >>= 1) s += __shfl_down(s, o);
    __syncthreads();
    if (lane == 0) wred[wid] = s;
    __syncthreads();
    if (t == 0) {
        float z = 0.f;
        #pragma unroll
        for (int i = 0; i < 16; ++i) z += wred[i];
        bcast = z;
    }
    __syncthreads();
    float inv_dn = 1.0f / (bcast + EPSF);

    // ---- loss partials ----
    float p1 = 0.f, p2 = 0.f;
    if (t < C_SZ) {
        float logp = __logf(e * inv_dn + EPSF);
        p2 = -soft[(size_t)srow_s * C_SZ + t] * logp;
        if (t == tgt_s) p1 = -logp;
    }
    #pragma unroll
    for (int o = 32; o; o >>= 1) {
        p1 += __shfl_down(p1, o);
        p2 += __shfl_down(p2, o);
    }
    __syncthreads();
    if (lane == 0) { wred[wid] = p1; wred2[wid] = p2; }
    __syncthreads();
    if (t == 0) {
        float z1 = 0.f, z2 = 0.f;
        #pragma unroll
        for (int i = 0; i < 16; ++i) { z1 += wred[i]; z2 += wred2[i]; }
        atomicAdd(&acc[0], z1);
        atomicAdd(&acc[1], z2);
        __threadfence();
        int done = atomicAdd(cnt, 1);
        if (done == (int)gridDim.x - 1) {
            float l1 = atomicAdd(&acc[0], 0.f) / (float)B_SZ;
            float l2 = atomicAdd(&acc[1], 0.f) / (float)B_SZ;
            out[0] = (cur_epoch[0] == 0) ? l1 : 0.5f * (l1 + l2);
        }
    }
}

extern "C" void kernel_launch(void* const* d_in, const int* in_sizes, int n_in,
                              void* d_out, int out_size, void* d_ws, size_t ws_size,
                              hipStream_t stream) {
    const float* feat     = (const float*)d_in[0];
    const float* features = (const float*)d_in[1];
    const float* soft     = (const float*)d_in[2];
    const int* indexes    = (const int*)d_in[3];
    const int* labels     = (const int*)d_in[4];
    const int* bil        = (const int*)d_in[5];
    const int* cur_epoch  = (const int*)d_in[6];

    char* ws = (char*)d_ws;
    float* fct   = (float*)(ws + OFF_FCT);
    int* nums    = (int*)(ws + OFF_NUMS);
    float* acc   = (float*)(ws + OFF_ACC);
    int* cnt     = (int*)(ws + OFF_CNT);
    int* offs    = (int*)(ws + OFF_OFFS);
    int* run     = (int*)(ws + OFF_RUN);
    int* members = (int*)(ws + OFF_MEMB);

    // zero nums + acc + cnt in one shot (contiguous)
    hipMemsetAsync(ws + OFF_NUMS, 0, 4012, stream);

    k_hist<<<M_SZ / 256, 256, 0, stream>>>(labels, nums);
    k_scan<<<1, 1024, 0, stream>>>(nums, offs, run);
    k_scatter<<<M_SZ / 256, 256, 0, stream>>>(labels, run, members);
    k_classsum<<<C_SZ, 256, 0, stream>>>(features, members, offs, nums, fct);
    k_loss<<<B_SZ, 1024, 0, stream>>>(feat, fct, nums, soft, indexes, labels,
                                      bil, cur_epoch, acc, cnt, (float*)d_out);
}

// Round 4
// 63.569 us; speedup vs baseline: 2.2492x; 1.4719x over previous
//
#include <hip/hip_runtime.h>

#define B_SZ 256
#define D_SZ 256
#define M_SZ 65536
#define C_SZ 1000
#define TEMP 0.05f
#define EPSF 1e-6f

#define NBLK_SORT 32
#define CHUNK (M_SZ / NBLK_SORT)   // 2048 labels per sort block

// ---- ws layout (bytes) ----
#define OFF_FCT     0          // float[D_SZ*C_SZ] = 1,024,000 B (transposed, pre-scaled)
#define OFF_NUMS    1024000    // int[C_SZ]
#define OFF_OFFS    1028000    // int[C_SZ]
#define OFF_ACC     1032000    // float[2]
#define OFF_CNT     1032008    // int[1]
#define OFF_COUNTS  1032064    // int[NBLK_SORT*C_SZ] = 128,000 B
#define OFF_BASE    1160064    // int[NBLK_SORT*C_SZ] = 128,000 B
#define OFF_MEMB    1288064    // int[M_SZ] = 262,144 B

// Pass 1: per-block private LDS histogram of a contiguous 2048-label chunk.
// No global atomics. Block 0 also zeroes acc/cnt (visible to later kernels
// via kernel-boundary release).
__launch_bounds__(1024)
__global__ void k_hist(const int* __restrict__ labels, int* __restrict__ counts,
                       float* __restrict__ acc, int* __restrict__ cnt) {
    __shared__ int h[C_SZ];
    int t = threadIdx.x, b = blockIdx.x;
    if (t < C_SZ) h[t] = 0;
    if (b == 0 && t == 0) { acc[0] = 0.f; acc[1] = 0.f; cnt[0] = 0; }
    __syncthreads();
    int start = b * CHUNK;
    #pragma unroll
    for (int k = 0; k < CHUNK / 1024; ++k)
        atomicAdd(&h[labels[start + k * 1024 + t]], 1);  // LDS atomic
    __syncthreads();
    if (t < C_SZ) counts[b * C_SZ + t] = h[t];
}

// Pass 2 (1 block): totals -> nums, exclusive scan -> offs, per-sort-block
// bases base[b][c].
__launch_bounds__(1024)
__global__ void k_scanbase(const int* __restrict__ counts, int* __restrict__ nums,
                           int* __restrict__ offs, int* __restrict__ base) {
    __shared__ int sc[1024];
    int t = threadIdx.x;
    int tot = 0;
    if (t < C_SZ) {
        #pragma unroll
        for (int b = 0; b < NBLK_SORT; ++b) tot += counts[b * C_SZ + t];
    }
    sc[t] = tot;
    __syncthreads();
    for (int d = 1; d < 1024; d <<= 1) {
        int v = (t >= d) ? sc[t - d] : 0;
        __syncthreads();
        sc[t] += v;
        __syncthreads();
    }
    if (t < C_SZ) {
        int e = sc[t] - tot;
        nums[t] = tot;
        offs[t] = e;
        int run = e;
        #pragma unroll
        for (int b = 0; b < NBLK_SORT; ++b) {
            base[b * C_SZ + t] = run;
            run += counts[b * C_SZ + t];
        }
    }
}

// Pass 3: scatter with LDS cursors seeded from base — LDS atomics only.
__launch_bounds__(1024)
__global__ void k_scatter(const int* __restrict__ labels, const int* __restrict__ base,
                          int* __restrict__ members) {
    __shared__ int cur[C_SZ];
    int t = threadIdx.x, b = blockIdx.x;
    if (t < C_SZ) cur[t] = base[b * C_SZ + t];
    __syncthreads();
    int start = b * CHUNK;
    #pragma unroll
    for (int k = 0; k < CHUNK / 1024; ++k) {
        int m = start + k * 1024 + t;
        int pos = atomicAdd(&cur[labels[m]], 1);  // LDS atomic
        members[pos] = m;
    }
}

// One block per class: sum member rows, 8-way unrolled for MLP. Writes
// transposed + pre-scaled: fct[d*C + c] = sum / (TEMP * max(n,1)).
__launch_bounds__(256)
__global__ void k_classsum(const float* __restrict__ features,
                           const int* __restrict__ members,
                           const int* __restrict__ offs,
                           const int* __restrict__ nums,
                           float* __restrict__ fct) {
    int c = blockIdx.x;
    int t = threadIdx.x;
    int beg = offs[c], n = nums[c];
    float a0 = 0.f, a1 = 0.f, a2 = 0.f, a3 = 0.f;
    float a4 = 0.f, a5 = 0.f, a6 = 0.f, a7 = 0.f;
    int i = 0;
    for (; i + 8 <= n; i += 8) {
        int r0 = members[beg + i + 0];
        int r1 = members[beg + i + 1];
        int r2 = members[beg + i + 2];
        int r3 = members[beg + i + 3];
        int r4 = members[beg + i + 4];
        int r5 = members[beg + i + 5];
        int r6 = members[beg + i + 6];
        int r7 = members[beg + i + 7];
        a0 += features[(size_t)r0 * D_SZ + t];
        a1 += features[(size_t)r1 * D_SZ + t];
        a2 += features[(size_t)r2 * D_SZ + t];
        a3 += features[(size_t)r3 * D_SZ + t];
        a4 += features[(size_t)r4 * D_SZ + t];
        a5 += features[(size_t)r5 * D_SZ + t];
        a6 += features[(size_t)r6 * D_SZ + t];
        a7 += features[(size_t)r7 * D_SZ + t];
    }
    for (; i < n; ++i) a0 += features[(size_t)members[beg + i] * D_SZ + t];
    float s = ((a0 + a1) + (a2 + a3)) + ((a4 + a5) + (a6 + a7));
    float scale = 1.0f / (TEMP * (float)(n > 0 ? n : 1));
    fct[(size_t)t * C_SZ + c] = s * scale;
}

// One block (1024 thr) per TWO batch rows (2r, 2r+1); thread t = class t.
// Halves redundant fct L2 traffic vs 1 row/block.
__launch_bounds__(1024)
__global__ void k_loss(const float* __restrict__ feat,
                       const float* __restrict__ fct,
                       const int* __restrict__ nums,
                       const float* __restrict__ soft,
                       const int* __restrict__ indexes,
                       const int* __restrict__ labels,
                       const int* __restrict__ bil,
                       const int* __restrict__ cur_epoch,
                       float* __restrict__ acc, int* __restrict__ cnt,
                       float* __restrict__ out) {
    __shared__ float xs0[D_SZ], xs1[D_SZ];
    __shared__ float wred[16], wred2[16];
    __shared__ float bc0, bc1;
    __shared__ int tgt0, tgt1, sr0, sr1;

    int t = threadIdx.x;
    int lane = t & 63, wid = t >> 6;
    int r0 = blockIdx.x * 2;

    if (t == 0) {
        tgt0 = labels[indexes[r0]];
        tgt1 = labels[indexes[r0 + 1]];
        sr0 = bil[r0];
        sr1 = bil[r0 + 1];
    }

    // ---- normalize rows 2r,2r+1 (contiguous 512 floats) ----
    float v = (t < 512) ? feat[(size_t)r0 * D_SZ + t] : 0.f;
    float s = v * v;
    #pragma unroll
    for (int o = 32; o; o >>= 1) s += __shfl_down(s, o);
    if (lane == 0) wred[wid] = s;  // waves 0-3 = row0, 4-7 = row1
    __syncthreads();
    if (t == 0) {
        bc0 = fmaxf(sqrtf(wred[0] + wred[1] + wred[2] + wred[3]), 1e-12f);
        bc1 = fmaxf(sqrtf(wred[4] + wred[5] + wred[6] + wred[7]), 1e-12f);
    }
    __syncthreads();
    if (t < 256) xs0[t] = v / bc0;
    else if (t < 512) xs1[t - 256] = v / bc1;
    __syncthreads();

    // ---- sim + exp for class t, both rows ----
    float a0 = 0.f, a1 = 0.f;
    if (t < C_SZ) {
        #pragma unroll 4
        for (int i = 0; i < D_SZ; ++i) {
            float f = fct[(size_t)i * C_SZ + t];  // coalesced across lanes
            a0 = fmaf(xs0[i], f, a0);
            a1 = fmaf(xs1[i], f, a1);
        }
    }
    float mk = (t < C_SZ && nums[t] > 0) ? 1.f : 0.f;
    float e0 = mk * __expf(a0);
    float e1 = mk * __expf(a1);

    // ---- denominators over classes (both rows at once) ----
    float s0 = e0, s1 = e1;
    #pragma unroll
    for (int o = 32; o; o >>= 1) {
        s0 += __shfl_down(s0, o);
        s1 += __shfl_down(s1, o);
    }
    if (lane == 0) { wred[wid] = s0; wred2[wid] = s1; }
    __syncthreads();
    if (t == 0) {
        float z0 = 0.f, z1 = 0.f;
        #pragma unroll
        for (int i = 0; i < 16; ++i) { z0 += wred[i]; z1 += wred2[i]; }
        bc0 = z0; bc1 = z1;
    }
    __syncthreads();
    float inv0 = 1.0f / (bc0 + EPSF);
    float inv1 = 1.0f / (bc1 + EPSF);

    // ---- loss partials ----
    float p1 = 0.f, p2 = 0.f;
    if (t < C_SZ) {
        float lp0 = __logf(e0 * inv0 + EPSF);
        float lp1 = __logf(e1 * inv1 + EPSF);
        p2 = -(soft[(size_t)sr0 * C_SZ + t] * lp0 + soft[(size_t)sr1 * C_SZ + t] * lp1);
        if (t == tgt0) p1 -= lp0;
        if (t == tgt1) p1 -= lp1;
    }
    #pragma unroll
    for (int o = 32; o; o >>= 1) {
        p1 += __shfl_down(p1, o);
        p2 += __shfl_down(p2, o);
    }
    __syncthreads();
    if (lane == 0) { wred[wid] = p1; wred2[wid] = p2; }
    __syncthreads();
    if (t == 0) {
        float z1 = 0.f, z2 = 0.f;
        #pragma unroll
        for (int i = 0; i < 16; ++i) { z1 += wred[i]; z2 += wred2[i]; }
        atomicAdd(&acc[0], z1);
        atomicAdd(&acc[1], z2);
        __threadfence();
        int done = atomicAdd(cnt, 1);
        if (done == (int)gridDim.x - 1) {
            float l1 = atomicAdd(&acc[0], 0.f) / (float)B_SZ;
            float l2 = atomicAdd(&acc[1], 0.f) / (float)B_SZ;
            out[0] = (cur_epoch[0] == 0) ? l1 : 0.5f * (l1 + l2);
        }
    }
}

extern "C" void kernel_launch(void* const* d_in, const int* in_sizes, int n_in,
                              void* d_out, int out_size, void* d_ws, size_t ws_size,
                              hipStream_t stream) {
    const float* feat     = (const float*)d_in[0];
    const float* features = (const float*)d_in[1];
    const float* soft     = (const float*)d_in[2];
    const int* indexes    = (const int*)d_in[3];
    const int* labels     = (const int*)d_in[4];
    const int* bil        = (const int*)d_in[5];
    const int* cur_epoch  = (const int*)d_in[6];

    char* ws = (char*)d_ws;
    float* fct   = (float*)(ws + OFF_FCT);
    int* nums    = (int*)(ws + OFF_NUMS);
    int* offs    = (int*)(ws + OFF_OFFS);
    float* acc   = (float*)(ws + OFF_ACC);
    int* cnt     = (int*)(ws + OFF_CNT);
    int* counts  = (int*)(ws + OFF_COUNTS);
    int* base    = (int*)(ws + OFF_BASE);
    int* members = (int*)(ws + OFF_MEMB);

    k_hist<<<NBLK_SORT, 1024, 0, stream>>>(labels, counts, acc, cnt);
    k_scanbase<<<1, 1024, 0, stream>>>(counts, nums, offs, base);
    k_scatter<<<NBLK_SORT, 1024, 0, stream>>>(labels, base, members);
    k_classsum<<<C_SZ, 256, 0, stream>>>(features, members, offs, nums, fct);
    k_loss<<<B_SZ / 2, 1024, 0, stream>>>(feat, fct, nums, soft, indexes, labels,
                                          bil, cur_epoch, acc, cnt, (float*)d_out);
}